// Round 3
// baseline (216.632 us; speedup 1.0000x reference)
//
#include <hip/hip_runtime.h>

// SimpleSNN: T=16, B=4096, N_IN=784, N_HID=256, N_OUT=10
// Pipeline:
//   conv_w     : W1 -> W_hi/W_lo bf16 (RNE split), K padded 784->800
//   gemm1_mfma : C1 = X @ W1.T + b1 via bf16 MFMA, two-term (hi+lo) exact split.
//                NO LDS, NO barriers: fragments loaded straight from global
//                (A: fp32->bf16 truncate-pack in regs, exact for {0,1};
//                 B: 0.8 MB, L2-resident). Compiler pipelines freely.
//   lif1       : LIF recurrence over t per (b,n); z1 overwrites C1 in place
//   gemm2_f32  : C2 = z1 @ W2.T + b2
//   lif2       : LIF recurrence + spike count -> out

#define T_STEPS 16
#define B_SZ    4096
#define N_IN    784
#define N_HID   256
#define N_OUT   10
#define M_TOT   (T_STEPS * B_SZ)   // 65536
#define KPAD    800                // 784 padded to 25*32
#define BKS     32

typedef __bf16 bf16x8 __attribute__((ext_vector_type(8)));
typedef float  f32x4  __attribute__((ext_vector_type(4)));
typedef unsigned short ushort_t;
typedef unsigned int   u32;

// ---------------- conv_w: split W1 into hi/lo bf16, pad K to 800 -----------
__device__ __forceinline__ unsigned short bf16_rne(float f) {
    u32 u = __builtin_bit_cast(u32, f);
    u += 0x7fffu + ((u >> 16) & 1u);
    return (unsigned short)(u >> 16);
}

__global__ __launch_bounds__(256) void conv_w(
    const float* __restrict__ W1,
    ushort_t* __restrict__ Whi, ushort_t* __restrict__ Wlo)
{
    const int idx = blockIdx.x * 256 + threadIdx.x;   // over 256*800
    if (idx >= N_HID * KPAD) return;
    const int n = idx / KPAD, k = idx % KPAD;
    unsigned short h = 0, l = 0;
    if (k < N_IN) {
        const float w = W1[n * N_IN + k];
        h = bf16_rne(w);
        const float hf = __builtin_bit_cast(float, (u32)h << 16);
        l = bf16_rne(w - hf);
    }
    Whi[idx] = h;
    Wlo[idx] = l;
}

// ---------------- gemm1: MFMA bf16 split, no-LDS, 128x256 tile, 512 thr ----
// Wave w (0..7): wm = w>>2 (m 64-subtile), wn = w&3 (n 64-subtile).
// Fragment layout (mfma_f32_16x16x32_bf16): lane holds A[row=lane&15][k-slice
// (lane>>4)*8 .. +8]; loaded directly from global.
__device__ __forceinline__ u32 pack_hi16(u32 a, u32 b) {
    return (a >> 16) | (b & 0xffff0000u);   // bf16 truncation; exact for {0,1}
}

__global__ __launch_bounds__(512, 2) void gemm1_mfma(
    const float* __restrict__ X,
    const ushort_t* __restrict__ Whi,
    const ushort_t* __restrict__ Wlo,
    const float* __restrict__ b1,
    float* __restrict__ C)
{
    const int tid  = threadIdx.x;
    const int lane = tid & 63;
    const int w    = tid >> 6;
    const int wm   = w >> 2;
    const int wn   = w & 3;
    const int m0   = blockIdx.x * 128;
    const int ls   = lane >> 4;     // k-slice 0..3 (8 elems each)
    const int lr   = lane & 15;     // row within fragment

    const float* aP[4];
    #pragma unroll
    for (int i = 0; i < 4; ++i)
        aP[i] = X + (size_t)(m0 + wm * 64 + i * 16 + lr) * N_IN + ls * 8;

    const ushort_t* bhP[4];
    const ushort_t* blP[4];
    #pragma unroll
    for (int j = 0; j < 4; ++j) {
        const size_t ro = (size_t)(wn * 64 + j * 16 + lr) * KPAD + ls * 8;
        bhP[j] = Whi + ro;
        blP[j] = Wlo + ro;
    }

    f32x4 acc[4][4];
    #pragma unroll
    for (int i = 0; i < 4; ++i)
        #pragma unroll
        for (int j = 0; j < 4; ++j)
            #pragma unroll
            for (int q = 0; q < 4; ++q)
                acc[i][j][q] = 0.0f;

    auto kstep = [&](int kt, bool tail) {
        const int k0 = kt * BKS;
        bf16x8 af[4];
        #pragma unroll
        for (int i = 0; i < 4; ++i) {
            uint4 pk = make_uint4(0u, 0u, 0u, 0u);
            if (!tail || ls < 2) {          // k0 + ls*8 < 784 always true here
                const uint4* s = reinterpret_cast<const uint4*>(aP[i] + k0);
                const uint4 q0 = s[0];
                const uint4 q1 = s[1];
                pk.x = pack_hi16(q0.x, q0.y);
                pk.y = pack_hi16(q0.z, q0.w);
                pk.z = pack_hi16(q1.x, q1.y);
                pk.w = pack_hi16(q1.z, q1.w);
            }
            af[i] = __builtin_bit_cast(bf16x8, pk);
        }
        bf16x8 bh[4], bl[4];
        #pragma unroll
        for (int j = 0; j < 4; ++j) {
            bh[j] = *reinterpret_cast<const bf16x8*>(bhP[j] + k0);
            bl[j] = *reinterpret_cast<const bf16x8*>(blP[j] + k0);
        }
        // hi pass then lo pass: identical accumulation order to the verified kernel
        #pragma unroll
        for (int i = 0; i < 4; ++i)
            #pragma unroll
            for (int j = 0; j < 4; ++j)
                acc[i][j] = __builtin_amdgcn_mfma_f32_16x16x32_bf16(
                    af[i], bh[j], acc[i][j], 0, 0, 0);
        #pragma unroll
        for (int i = 0; i < 4; ++i)
            #pragma unroll
            for (int j = 0; j < 4; ++j)
                acc[i][j] = __builtin_amdgcn_mfma_f32_16x16x32_bf16(
                    af[i], bl[j], acc[i][j], 0, 0, 0);
    };

    #pragma unroll 4
    for (int kt = 0; kt < 24; ++kt)     // k = 0..768, all slices < 784: no predicate
        kstep(kt, false);
    kstep(24, true);                    // k = 768..800: slices 2,3 are zero/padded

    // epilogue: C/D layout col=lane&15, row=(lane>>4)*4+q  (m89-verified)
    #pragma unroll
    for (int j = 0; j < 4; ++j) {
        const int col  = wn * 64 + j * 16 + lr;
        const float bb = b1[col];
        #pragma unroll
        for (int i = 0; i < 4; ++i) {
            const int rbase = m0 + wm * 64 + i * 16 + (ls << 2);
            #pragma unroll
            for (int q = 0; q < 4; ++q)
                C[(size_t)(rbase + q) * N_HID + col] = acc[i][j][q] + bb;
        }
    }
}

// ---------------- LIF1: per (b,n), loop t; overwrite C1 with z1 ------------
__global__ __launch_bounds__(256) void lif1_kernel(float* __restrict__ C1)
{
    const int g = blockIdx.x * 256 + threadIdx.x;   // b*256+n, < B*N_HID
    const size_t stride = (size_t)B_SZ * N_HID;
    float v = 0.0f, cur = 0.0f;
    #pragma unroll
    for (int t = 0; t < T_STEPS; ++t) {
        const size_t off = (size_t)t * stride + g;
        const float c = C1[off];
        const float vd = v + 0.1f * ((0.0f - v) + cur);
        const float id = cur - 0.2f * cur;
        const bool  sp = vd > 1.0f;
        C1[off] = sp ? 1.0f : 0.0f;
        v = sp ? 0.0f : vd;
        cur = id + c;
    }
}

// ---------------- GEMM2: M=65536, K=256, N=10; 64 rows/block, 640 thr ------
__global__ __launch_bounds__(640) void gemm2_f32(
    const float* __restrict__ Z, const float* __restrict__ W2,
    const float* __restrict__ b2, float* __restrict__ C2)
{
    __shared__ float zs[64 * 268];  // stride 268: 16B-aligned, %32==12 (bank spread)
    __shared__ float ws[N_OUT * N_HID];
    const int tid = threadIdx.x;
    const int m0 = blockIdx.x * 64;

    for (int idx = tid; idx < 4096; idx += 640) {     // 64x256 floats as float4
        const int r = idx >> 6;
        const int c = (idx & 63) << 2;
        *(float4*)&zs[r * 268 + c] =
            *(const float4*)&Z[(size_t)(m0 + r) * N_HID + c];
    }
    *(float4*)&ws[tid * 4] = *(const float4*)&W2[tid * 4];  // 640*4 = 2560 exactly
    __syncthreads();

    const int o = tid >> 6;       // 0..9 (one wave per output)
    const int r = tid & 63;       // row within tile
    float acc = b2[o];
    #pragma unroll
    for (int k = 0; k < N_HID; k += 4) {
        const float4 z4 = *(const float4*)&zs[r * 268 + k];
        const float4 w4 = *(const float4*)&ws[o * N_HID + k];
        acc += z4.x * w4.x + z4.y * w4.y + z4.z * w4.z + z4.w * w4.w;
    }
    C2[(size_t)(m0 + r) * N_OUT + o] = acc;
}

// ---------------- LIF2: per (b,o), loop t; accumulate spike count ----------
__global__ __launch_bounds__(256) void lif2_kernel(
    const float* __restrict__ C2, float* __restrict__ out)
{
    const int g = blockIdx.x * 256 + threadIdx.x;   // b*10+o, < 40960
    const int stride = B_SZ * N_OUT;
    float v = 0.0f, cur = 0.0f, s = 0.0f;
    #pragma unroll
    for (int t = 0; t < T_STEPS; ++t) {
        const float c = C2[t * stride + g];
        const float vd = v + 0.1f * ((0.0f - v) + cur);
        const float id = cur - 0.2f * cur;
        const bool  sp = vd > 1.0f;
        s += sp ? 1.0f : 0.0f;
        v = sp ? 0.0f : vd;
        cur = id + c;
    }
    out[g] = s;
}

extern "C" void kernel_launch(void* const* d_in, const int* in_sizes, int n_in,
                              void* d_out, int out_size, void* d_ws, size_t ws_size,
                              hipStream_t stream)
{
    const float* X  = (const float*)d_in[0];   // (T,B,784) binary spikes
    const float* W1 = (const float*)d_in[1];   // (256,784)
    const float* b1 = (const float*)d_in[2];   // (256)
    const float* W2 = (const float*)d_in[3];   // (10,256)
    const float* b2 = (const float*)d_in[4];   // (10)
    float* out = (float*)d_out;                // (4096,10)

    ushort_t* Whi = (ushort_t*)d_ws;                       // 256*800 bf16
    ushort_t* Wlo = Whi + N_HID * KPAD;                    // 256*800 bf16
    float* C1 = (float*)((char*)d_ws + (1 << 20));         // 65536x256 fp32 (reused as z1)
    float* C2 = C1 + (size_t)M_TOT * N_HID;                // 65536x10 fp32

    conv_w<<<(N_HID * KPAD + 255) / 256, 256, 0, stream>>>(W1, Whi, Wlo);

    gemm1_mfma<<<M_TOT / 128, 512, 0, stream>>>(X, Whi, Wlo, b1, C1);

    lif1_kernel<<<(B_SZ * N_HID) / 256, 256, 0, stream>>>(C1);

    gemm2_f32<<<M_TOT / 64, 640, 0, stream>>>(C1, W2, b2, C2);

    lif2_kernel<<<(B_SZ * N_OUT) / 256, 256, 0, stream>>>(C2, out);
}

// Round 4
// 152.676 us; speedup vs baseline: 1.4189x; 1.4189x over previous
//
#include <hip/hip_runtime.h>

// SimpleSNN: T=16, B=4096, N_IN=784, N_HID=256, N_OUT=10
// gemm1: bf16 MFMA two-term (hi+lo) exact split, m97-shape structure:
//   128x128 tile, 256 thr (4 waves of 64x64), BK=32, double-buffered LDS
//   (48KB -> 3 blocks/CU), ONE barrier per k-step, A reg-staged
//   (fp32->bf16 truncate, exact for {0,1}) issued BEFORE B global_load_lds
//   so the pack's vmcnt wait leaves B prefetches in flight.

#define T_STEPS 16
#define B_SZ    4096
#define N_IN    784
#define N_HID   256
#define N_OUT   10
#define M_TOT   (T_STEPS * B_SZ)   // 65536
#define KPAD    800                // 784 padded to 25*32
#define NT      25                 // k-steps

typedef __bf16 bf16x8 __attribute__((ext_vector_type(8)));
typedef float  f32x4  __attribute__((ext_vector_type(4)));
typedef unsigned short ushort_t;
typedef unsigned int   u32;

// ---------------- conv_w: split W1 into hi/lo bf16, pad K to 800 -----------
__device__ __forceinline__ unsigned short bf16_rne(float f) {
    u32 u = __builtin_bit_cast(u32, f);
    u += 0x7fffu + ((u >> 16) & 1u);
    return (unsigned short)(u >> 16);
}

__global__ __launch_bounds__(256) void conv_w(
    const float* __restrict__ W1,
    ushort_t* __restrict__ Whi, ushort_t* __restrict__ Wlo)
{
    const int idx = blockIdx.x * 256 + threadIdx.x;   // over 256*800
    if (idx >= N_HID * KPAD) return;
    const int n = idx / KPAD, k = idx % KPAD;
    unsigned short hh = 0, ll = 0;
    if (k < N_IN) {
        const float wv = W1[n * N_IN + k];
        hh = bf16_rne(wv);
        const float hf = __builtin_bit_cast(float, (u32)hh << 16);
        ll = bf16_rne(wv - hf);
    }
    Whi[idx] = hh;
    Wlo[idx] = ll;
}

// ---------------- gemm1 ----------------------------------------------------
__device__ __forceinline__ u32 pack_hi16(u32 a, u32 b) {
    return (a >> 16) | (b & 0xffff0000u);   // bf16 truncation; exact for {0,1}
}

__global__ __launch_bounds__(256, 3) void gemm1_mfma(
    const float* __restrict__ X,
    const ushort_t* __restrict__ Whi,
    const ushort_t* __restrict__ Wlo,
    const float* __restrict__ b1,
    float* __restrict__ C)
{
    // phys layout [row][slot0..3] of 8 bf16; logical slot l stored at l^(row&3)
    __shared__ ushort_t As[2][128 * 32];
    __shared__ ushort_t Bh[2][128 * 32];
    __shared__ ushort_t Bl[2][128 * 32];

    const int tid  = threadIdx.x;
    const int lane = tid & 63;
    const int w    = tid >> 6;         // wave 0..3
    const int wm   = w >> 1;           // m 64-subtile
    const int wn   = w & 1;            // n 64-subtile
    const int m0   = blockIdx.x * 128;
    const int n0   = blockIdx.y * 128;
    const int ls   = lane >> 4;        // logical k-slot 0..3
    const int lr   = lane & 15;

    // ---- A staging map: thread -> row ar, k-half h (16 floats) ----
    const int ar = tid >> 1;           // 0..127
    const int h  = tid & 1;
    const float* aBase = X + (size_t)(m0 + ar) * N_IN + h * 16;
    const int aw0 = ar * 32 + (((2 * h)     ^ (ar & 3)) << 3);
    const int aw1 = ar * 32 + (((2 * h + 1) ^ (ar & 3)) << 3);

    // ---- B staging map: per wave, 2 issues x {Bh,Bl}; 16 rows/issue ----
    const int brow0 = w * 32 + (lane >> 2);          // ii=0 row
    const int bcs0  = (lane & 3) ^ (brow0 & 3);
    const int brow1 = brow0 + 16;                    // ii=1 row
    const int bcs1  = (lane & 3) ^ (brow1 & 3);

    f32x4 acc[4][4];
    #pragma unroll
    for (int i = 0; i < 4; ++i)
        #pragma unroll
        for (int j = 0; j < 4; ++j)
            #pragma unroll
            for (int q = 0; q < 4; ++q)
                acc[i][j][q] = 0.0f;

    float4 aregs[4];
    auto loadA = [&](int kt) {
        const int k0 = kt * 32;
        if (k0 + h * 16 < N_IN) {      // whole 16-chunk valid or whole invalid
            const float4* s = reinterpret_cast<const float4*>(aBase + k0);
            aregs[0] = s[0]; aregs[1] = s[1]; aregs[2] = s[2]; aregs[3] = s[3];
        } else {
            aregs[0] = aregs[1] = aregs[2] = aregs[3] = make_float4(0.f, 0.f, 0.f, 0.f);
        }
    };
    auto packA = [&](int bi) {
        uint4 w0, w1;
        w0.x = pack_hi16(__builtin_bit_cast(u32, aregs[0].x), __builtin_bit_cast(u32, aregs[0].y));
        w0.y = pack_hi16(__builtin_bit_cast(u32, aregs[0].z), __builtin_bit_cast(u32, aregs[0].w));
        w0.z = pack_hi16(__builtin_bit_cast(u32, aregs[1].x), __builtin_bit_cast(u32, aregs[1].y));
        w0.w = pack_hi16(__builtin_bit_cast(u32, aregs[1].z), __builtin_bit_cast(u32, aregs[1].w));
        w1.x = pack_hi16(__builtin_bit_cast(u32, aregs[2].x), __builtin_bit_cast(u32, aregs[2].y));
        w1.y = pack_hi16(__builtin_bit_cast(u32, aregs[2].z), __builtin_bit_cast(u32, aregs[2].w));
        w1.z = pack_hi16(__builtin_bit_cast(u32, aregs[3].x), __builtin_bit_cast(u32, aregs[3].y));
        w1.w = pack_hi16(__builtin_bit_cast(u32, aregs[3].z), __builtin_bit_cast(u32, aregs[3].w));
        *reinterpret_cast<uint4*>(&As[bi][aw0]) = w0;
        *reinterpret_cast<uint4*>(&As[bi][aw1]) = w1;
    };
    auto issueB = [&](int kt, int bi) {
        const int k0 = kt * 32;
        const size_t g0 = (size_t)(n0 + brow0) * KPAD + k0 + bcs0 * 8;
        const size_t g1 = (size_t)(n0 + brow1) * KPAD + k0 + bcs1 * 8;
        ushort_t* d0 = &Bh[bi][(w * 32) * 32];
        ushort_t* d1 = &Bh[bi][(w * 32 + 16) * 32];
        ushort_t* e0 = &Bl[bi][(w * 32) * 32];
        ushort_t* e1 = &Bl[bi][(w * 32 + 16) * 32];
        __builtin_amdgcn_global_load_lds(
            (const __attribute__((address_space(1))) void*)(Whi + g0),
            (__attribute__((address_space(3))) void*)d0, 16, 0, 0);
        __builtin_amdgcn_global_load_lds(
            (const __attribute__((address_space(1))) void*)(Whi + g1),
            (__attribute__((address_space(3))) void*)d1, 16, 0, 0);
        __builtin_amdgcn_global_load_lds(
            (const __attribute__((address_space(1))) void*)(Wlo + g0),
            (__attribute__((address_space(3))) void*)e0, 16, 0, 0);
        __builtin_amdgcn_global_load_lds(
            (const __attribute__((address_space(1))) void*)(Wlo + g1),
            (__attribute__((address_space(3))) void*)e1, 16, 0, 0);
    };

    // ---- prologue: stage tile 0 (A loads issued BEFORE B so pack waits
    //      only on A, leaving B in flight) ----
    loadA(0);
    issueB(0, 0);
    packA(0);

    // fragment read offsets (phys slot = ls ^ (row&3); row&3 == lr&3 here)
    const int fp = (ls ^ (lr & 3)) << 3;
    int aoff[4], boff[4];
    #pragma unroll
    for (int i = 0; i < 4; ++i) aoff[i] = (wm * 64 + i * 16 + lr) * 32 + fp;
    #pragma unroll
    for (int j = 0; j < 4; ++j) boff[j] = (wn * 64 + j * 16 + lr) * 32 + fp;

    int buf = 0;
    for (int kt = 0; kt < NT; ++kt) {
        __syncthreads();               // LDS[buf] staged; prior reads complete

        bf16x8 af[4], bfh[4], bfl[4];
        #pragma unroll
        for (int i = 0; i < 4; ++i)
            af[i] = *reinterpret_cast<const bf16x8*>(&As[buf][aoff[i]]);
        #pragma unroll
        for (int j = 0; j < 4; ++j)
            bfh[j] = *reinterpret_cast<const bf16x8*>(&Bh[buf][boff[j]]);

        if (kt + 1 < NT) {             // prefetch next tile: A first, then B
            loadA(kt + 1);
            issueB(kt + 1, buf ^ 1);
        }

        #pragma unroll
        for (int i = 0; i < 4; ++i)
            #pragma unroll
            for (int j = 0; j < 4; ++j)
                acc[i][j] = __builtin_amdgcn_mfma_f32_16x16x32_bf16(
                    af[i], bfh[j], acc[i][j], 0, 0, 0);

        #pragma unroll
        for (int j = 0; j < 4; ++j)
            bfl[j] = *reinterpret_cast<const bf16x8*>(&Bl[buf][boff[j]]);

        #pragma unroll
        for (int i = 0; i < 4; ++i)
            #pragma unroll
            for (int j = 0; j < 4; ++j)
                acc[i][j] = __builtin_amdgcn_mfma_f32_16x16x32_bf16(
                    af[i], bfl[j], acc[i][j], 0, 0, 0);

        if (kt + 1 < NT) packA(buf ^ 1);   // vmcnt waits only A (issued first)
        buf ^= 1;
    }

    // epilogue: C/D layout col=lane&15, row=(lane>>4)*4+q (m89-verified)
    #pragma unroll
    for (int j = 0; j < 4; ++j) {
        const int col  = n0 + wn * 64 + j * 16 + lr;
        const float bb = b1[col];
        #pragma unroll
        for (int i = 0; i < 4; ++i) {
            const int rbase = m0 + wm * 64 + i * 16 + (ls << 2);
            #pragma unroll
            for (int q = 0; q < 4; ++q)
                C[(size_t)(rbase + q) * N_HID + col] = acc[i][j][q] + bb;
        }
    }
}

// ---------------- LIF1: per (b,n), loop t; overwrite C1 with z1 ------------
__global__ __launch_bounds__(256) void lif1_kernel(float* __restrict__ C1)
{
    const int g = blockIdx.x * 256 + threadIdx.x;
    const size_t stride = (size_t)B_SZ * N_HID;
    float v = 0.0f, cur = 0.0f;
    #pragma unroll
    for (int t = 0; t < T_STEPS; ++t) {
        const size_t off = (size_t)t * stride + g;
        const float c = C1[off];
        const float vd = v + 0.1f * ((0.0f - v) + cur);
        const float id = cur - 0.2f * cur;
        const bool  sp = vd > 1.0f;
        C1[off] = sp ? 1.0f : 0.0f;
        v = sp ? 0.0f : vd;
        cur = id + c;
    }
}

// ---------------- GEMM2: M=65536, K=256, N=10; 64 rows/block, 640 thr ------
__global__ __launch_bounds__(640) void gemm2_f32(
    const float* __restrict__ Z, const float* __restrict__ W2,
    const float* __restrict__ b2, float* __restrict__ C2)
{
    __shared__ float zs[64 * 268];
    __shared__ float ws[N_OUT * N_HID];
    const int tid = threadIdx.x;
    const int m0 = blockIdx.x * 64;

    for (int idx = tid; idx < 4096; idx += 640) {
        const int r = idx >> 6;
        const int c = (idx & 63) << 2;
        *(float4*)&zs[r * 268 + c] =
            *(const float4*)&Z[(size_t)(m0 + r) * N_HID + c];
    }
    *(float4*)&ws[tid * 4] = *(const float4*)&W2[tid * 4];
    __syncthreads();

    const int o = tid >> 6;
    const int r = tid & 63;
    float acc = b2[o];
    #pragma unroll
    for (int k = 0; k < N_HID; k += 4) {
        const float4 z4 = *(const float4*)&zs[r * 268 + k];
        const float4 w4 = *(const float4*)&ws[o * N_HID + k];
        acc += z4.x * w4.x + z4.y * w4.y + z4.z * w4.z + z4.w * w4.w;
    }
    C2[(size_t)(m0 + r) * N_OUT + o] = acc;
}

// ---------------- LIF2: per (b,o), loop t; accumulate spike count ----------
__global__ __launch_bounds__(256) void lif2_kernel(
    const float* __restrict__ C2, float* __restrict__ out)
{
    const int g = blockIdx.x * 256 + threadIdx.x;
    const int stride = B_SZ * N_OUT;
    float v = 0.0f, cur = 0.0f, s = 0.0f;
    #pragma unroll
    for (int t = 0; t < T_STEPS; ++t) {
        const float c = C2[t * stride + g];
        const float vd = v + 0.1f * ((0.0f - v) + cur);
        const float id = cur - 0.2f * cur;
        const bool  sp = vd > 1.0f;
        s += sp ? 1.0f : 0.0f;
        v = sp ? 0.0f : vd;
        cur = id + c;
    }
    out[g] = s;
}

extern "C" void kernel_launch(void* const* d_in, const int* in_sizes, int n_in,
                              void* d_out, int out_size, void* d_ws, size_t ws_size,
                              hipStream_t stream)
{
    const float* X  = (const float*)d_in[0];
    const float* W1 = (const float*)d_in[1];
    const float* b1 = (const float*)d_in[2];
    const float* W2 = (const float*)d_in[3];
    const float* b2 = (const float*)d_in[4];
    float* out = (float*)d_out;

    ushort_t* Whi = (ushort_t*)d_ws;                       // 256*800 bf16
    ushort_t* Wlo = Whi + N_HID * KPAD;                    // 256*800 bf16
    float* C1 = (float*)((char*)d_ws + (1 << 20));         // 65536x256 fp32
    float* C2 = C1 + (size_t)M_TOT * N_HID;                // 65536x10 fp32

    conv_w<<<(N_HID * KPAD + 255) / 256, 256, 0, stream>>>(W1, Whi, Wlo);

    gemm1_mfma<<<dim3(M_TOT / 128, N_HID / 128), 256, 0, stream>>>(X, Whi, Wlo, b1, C1);

    lif1_kernel<<<(B_SZ * N_HID) / 256, 256, 0, stream>>>(C1);

    gemm2_f32<<<M_TOT / 64, 640, 0, stream>>>(C1, W2, b2, C2);

    lif2_kernel<<<(B_SZ * N_OUT) / 256, 256, 0, stream>>>(C2, out);
}